// Round 6
// baseline (150.981 us; speedup 1.0000x reference)
//
#include <hip/hip_runtime.h>
#include <math.h>

#define B 16
#define N 200
#define HID 64
#define NH 2
#define D 32
#define EPSF 1e-12f

// 1/sqrt(32)
#define RSQRT_D 0.17677669529663687f

// ---------------- Kernel 1: projections + folded pos + order/dist scalars ----
// grid = B*N/4 blocks, 256 threads (4 rows per block, one wave per row)
__global__ __launch_bounds__(256) void k_proj(
    const float* __restrict__ x,
    const float* __restrict__ pk,
    const float* __restrict__ pv,
    const float* __restrict__ Wq, const float* __restrict__ bq,
    const float* __restrict__ Wk, const float* __restrict__ bk,
    const float* __restrict__ Wv, const float* __restrict__ bv,
    const float* __restrict__ order_w, const float* __restrict__ dist_w,
    float* __restrict__ q,
    float* __restrict__ kp,
    float* __restrict__ vp,
    float* __restrict__ qo, float* __restrict__ ko,
    float* __restrict__ qd, float* __restrict__ kd)
{
    __shared__ float sX[4][HID];
    const int tid = threadIdx.x;
    const int sub = tid >> 6;
    const int o   = tid & 63;
    const int row = blockIdx.x * 4 + sub;

    sX[sub][o] = x[row * HID + o];
    __syncthreads();

    float qv = bq[o], kv = bk[o], vv = bv[o];
    #pragma unroll 8
    for (int c = 0; c < HID; ++c) {
        const float xv = sX[sub][c];
        qv = fmaf(xv, Wq[o * HID + c], qv);
        kv = fmaf(xv, Wk[o * HID + c], kv);
        vv = fmaf(xv, Wv[o * HID + c], vv);
    }
    q [row * HID + o] = qv;
    kp[row * HID + o] = kv + pk[row * HID + o];
    vp[row * HID + o] = vv + pv[row * HID + o];

    const int d = o & 31;
    float qov = qv * order_w[d];
    float kov = kv * order_w[D + d];
    float qdv = qv * dist_w[d];
    float kdv = kv * dist_w[D + d];
    #pragma unroll
    for (int m = 16; m >= 1; m >>= 1) {
        qov += __shfl_xor(qov, m);
        kov += __shfl_xor(kov, m);
        qdv += __shfl_xor(qdv, m);
        kdv += __shfl_xor(kdv, m);
    }
    if (d == 0) {
        const int bb = row / N;
        const int ii = row - bb * N;
        const int h  = o >> 5;
        const int idx = (bb * NH + h) * N + ii;
        qo[idx] = qov;  ko[idx] = kov;
        qd[idx] = qdv;  kd[idx] = kdv;
    }
}

// ---------------- Kernel 2: S_pre[b,h,i,j] = (q.kp + order + dist)/sqrtD + mask
// grid = B*NH*8 blocks (i-tiles of 25), 256 threads. All operands L2-hot.
__global__ __launch_bounds__(256) void k_pre(
    const float* __restrict__ q, const float* __restrict__ kp,
    const float* __restrict__ amask,
    const float* __restrict__ qo, const float* __restrict__ ko,
    const float* __restrict__ qd, const float* __restrict__ kd,
    const float* __restrict__ order_b, const float* __restrict__ dist_b,
    const float* __restrict__ scalar,
    float* __restrict__ S_pre)        // [B*NH*N, N]
{
    __shared__ float sQ[25][33];
    __shared__ float sK[200][33];
    __shared__ float sGd[200];
    __shared__ float sQo[25], sQd[25];
    __shared__ float sKo[200], sKd[200];

    const int tid = threadIdx.x;
    const int bid = blockIdx.x;
    const int it  = bid & 7;          // i-tile
    const int bh  = bid >> 3;
    const int b   = bh >> 1;
    const int h   = bh & 1;
    const int i0  = it * 25;

    // stage KP h-slice [200][32]
    for (int e = tid; e < 200 * 32; e += 256) {
        const int j = e >> 5, d = e & 31;
        sK[j][d] = kp[((size_t)b * N + j) * HID + h * D + d];
    }
    // stage Q tile [25][32]
    for (int e = tid; e < 25 * 32; e += 256) {
        const int ii = e >> 5, d = e & 31;
        sQ[ii][d] = q[((size_t)b * N + i0 + ii) * HID + h * D + d];
    }
    for (int e = tid; e < 200; e += 256) {
        sGd[e] = logf((float)e + 1.0f);
        sKo[e] = ko[(size_t)bh * N + e];
        sKd[e] = kd[(size_t)bh * N + e];
    }
    if (tid < 25) {
        sQo[tid] = qo[(size_t)bh * N + i0 + tid];
        sQd[tid] = qd[(size_t)bh * N + i0 + tid];
    }
    const float ob = order_b[0];
    const float db = dist_b[0];
    const float sc = scalar[0];
    const float sc2h = 0.5f * sc * sc;
    __syncthreads();

    for (int e = tid; e < 25 * 200; e += 256) {
        const int ii = e / 200;
        const int jj = e - ii * 200;
        const int i  = i0 + ii;
        float dot = 0.0f;
        #pragma unroll
        for (int d = 0; d < 32; ++d)
            dot = fmaf(sQ[ii][d], sK[jj][d], dot);
        const float lo = sQo[ii] + sKo[jj] + ob;
        const float xs = (jj > i) ? -lo : lo;
        const float eo = -log1pf(expf(xs));
        const float pd = sQd[ii] + sKd[jj] + db;
        const int   ad = (jj > i) ? (jj - i) : (i - jj);
        const float dv = sGd[ad] - pd;
        const float ed = -sc2h * dv * dv;
        S_pre[((size_t)bh * N + i) * N + jj] =
            (dot + eo + ed) * RSQRT_D + amask[((size_t)b * N + i) * N + jj];
    }
}

// ---------------- Kernel 3: stream tk/tv only; softmax; P out; ctx_tv out ---
// grid = B*NH*N blocks, 64 threads = one wave per (b,h,i). Zero barriers.
// lane = 8*g + c; each tk/tv load instruction covers 8x128B dense segments.
__global__ __launch_bounds__(64) void k_attn(
    const float* __restrict__ q,
    const float* __restrict__ tk,     // [B,N,N,HID]
    const float* __restrict__ tv,
    const float* __restrict__ S_pre,  // [B*NH*N, N]
    float* __restrict__ P,            // [B*NH*N, N]
    float* __restrict__ ctx_tv)       // [B*N, HID]
{
    __shared__ float S_dot[256];
    __shared__ float SP[256];

    const int lane = threadIdx.x;
    const int g    = lane >> 3;       // j subgroup 0..7
    const int c    = lane & 7;        // float4 column 0..7
    const int bid  = blockIdx.x;      // bh*N + i
    const int bh   = bid / N;
    const int i    = bid - bh * N;
    const int b    = bh >> 1;
    const int h    = bh & 1;
    const int bi   = b * N + i;

    float4 qf = ((const float4*)(q + (size_t)bi * HID + h * D))[c];
    qf.x *= RSQRT_D; qf.y *= RSQRT_D; qf.z *= RSQRT_D; qf.w *= RSQRT_D;

    const float4* tkR = (const float4*)(tk + ((size_t)bi * N) * HID + h * D);
    const float4* tvR = (const float4*)(tv + ((size_t)bi * N) * HID + h * D);
    const float*  spr = S_pre + ((size_t)bh * N + i) * N;

    // S_pre row into registers (coalesced)
    const float sp0 = spr[lane];
    const float sp1 = spr[lane + 64];
    const float sp2 = spr[lane + 128];
    const float sp3 = (lane < 8) ? spr[lane + 192] : 0.0f;

    // ---- phase B: streaming tk dots, 2-deep pipeline ----
    float4 cur = tkR[(size_t)g * 16 + c];
    #pragma unroll
    for (int it = 0; it < 25; ++it) {
        float4 nxt;
        if (it < 24) nxt = tkR[(size_t)((it + 1) * 8 + g) * 16 + c];
        float part = qf.x * cur.x + qf.y * cur.y + qf.z * cur.z + qf.w * cur.w;
        part += __shfl_xor(part, 1);
        part += __shfl_xor(part, 2);
        part += __shfl_xor(part, 4);
        if (c == 0) S_dot[it * 8 + g] = part;
        cur = nxt;
    }
    asm volatile("s_waitcnt lgkmcnt(0)" ::: "memory");

    // ---- softmax over 200 ----
    const float s0 = sp0 + S_dot[lane];
    const float s1 = sp1 + S_dot[lane + 64];
    const float s2 = sp2 + S_dot[lane + 128];
    const float s3 = (lane < 8) ? (sp3 + S_dot[lane + 192]) : -INFINITY;
    float m = fmaxf(fmaxf(s0, s1), fmaxf(s2, s3));
    #pragma unroll
    for (int k = 32; k >= 1; k >>= 1) m = fmaxf(m, __shfl_xor(m, k));
    const float e0 = expf(s0 - m);
    const float e1 = expf(s1 - m);
    const float e2 = expf(s2 - m);
    const float e3 = (lane < 8) ? expf(s3 - m) : 0.0f;
    float t = e0 + e1 + e2 + e3;
    #pragma unroll
    for (int k = 32; k >= 1; k >>= 1) t += __shfl_xor(t, k);
    const float rinv = 1.0f / t;
    const float p0 = e0 * rinv, p1 = e1 * rinv, p2 = e2 * rinv, p3 = e3 * rinv;
    SP[lane]       = p0;
    SP[lane + 64]  = p1;
    SP[lane + 128] = p2;
    if (lane < 8) SP[lane + 192] = p3;

    // publish P for k_pv (coalesced row)
    float* prow = P + ((size_t)bh * N + i) * N;
    prow[lane]       = p0;
    prow[lane + 64]  = p1;
    prow[lane + 128] = p2;
    if (lane < 8) prow[lane + 192] = p3;

    asm volatile("s_waitcnt lgkmcnt(0)" ::: "memory");

    // ---- phase C: ctx_tv = sum_j p_j * tv[i,j], 2-deep pipeline ----
    float4 acc = make_float4(0.f, 0.f, 0.f, 0.f);
    float4 cv = tvR[(size_t)g * 16 + c];
    #pragma unroll
    for (int it = 0; it < 25; ++it) {
        float4 nv;
        if (it < 24) nv = tvR[(size_t)((it + 1) * 8 + g) * 16 + c];
        const float pj = SP[it * 8 + g];
        acc.x = fmaf(pj, cv.x, acc.x);
        acc.y = fmaf(pj, cv.y, acc.y);
        acc.z = fmaf(pj, cv.z, acc.z);
        acc.w = fmaf(pj, cv.w, acc.w);
        cv = nv;
    }
    #pragma unroll
    for (int k = 8; k <= 32; k <<= 1) {
        acc.x += __shfl_xor(acc.x, k);
        acc.y += __shfl_xor(acc.y, k);
        acc.z += __shfl_xor(acc.z, k);
        acc.w += __shfl_xor(acc.w, k);
    }
    if (g == 0)
        ((float4*)(ctx_tv + (size_t)bi * HID + h * D))[c] = acc;
}

// ---------------- Kernel 4: ctx_vp[b,h,i,:] = sum_j P[b,h,i,j] * vp_h[b,j,:]
// grid = B*NH*8 (i-tiles of 25), 256 threads. vp slice L2/LDS-resident.
__global__ __launch_bounds__(256) void k_pv(
    const float* __restrict__ P, const float* __restrict__ vp,
    float* __restrict__ ctx_vp)       // [B*NH*N, D]
{
    __shared__ float sV[200][33];
    const int tid = threadIdx.x;
    const int bid = blockIdx.x;
    const int it  = bid & 7;
    const int bh  = bid >> 3;
    const int b   = bh >> 1;
    const int h   = bh & 1;
    const int i0  = it * 25;

    for (int e = tid; e < 200 * 32; e += 256) {
        const int j = e >> 5, d = e & 31;
        sV[j][d] = vp[((size_t)b * N + j) * HID + h * D + d];
    }
    __syncthreads();

    for (int e = tid; e < 25 * 32; e += 256) {
        const int ii = e >> 5, d = e & 31;
        const float* pr = P + ((size_t)bh * N + i0 + ii) * N;
        float acc = 0.0f;
        #pragma unroll 8
        for (int j = 0; j < 200; ++j)
            acc = fmaf(pr[j], sV[j][d], acc);
        ctx_vp[((size_t)bh * N + i0 + ii) * D + d] = acc;
    }
}

// ---------------- Kernel 5: combine + output proj + residual + LayerNorm ---
__global__ __launch_bounds__(256) void k_out(
    const float* __restrict__ ctx_tv, const float* __restrict__ ctx_vp,
    const float* __restrict__ x,
    const float* __restrict__ Wd, const float* __restrict__ bd,
    const float* __restrict__ ln_g, const float* __restrict__ ln_b,
    float* __restrict__ out)
{
    __shared__ float sC[4][HID];
    const int tid = threadIdx.x;
    const int sub = tid >> 6;
    const int o   = tid & 63;
    const int row = blockIdx.x * 4 + sub;
    const int b   = row / N;
    const int i   = row - b * N;
    const int h   = o >> 5;

    sC[sub][o] = ctx_tv[(size_t)row * HID + o]
               + ctx_vp[((size_t)(b * NH + h) * N + i) * D + (o & 31)];
    __syncthreads();

    float hv = bd[o] + x[(size_t)row * HID + o];
    #pragma unroll 8
    for (int c = 0; c < HID; ++c)
        hv = fmaf(sC[sub][c], Wd[o * HID + c], hv);

    float sum = hv;
    #pragma unroll
    for (int m = 32; m >= 1; m >>= 1) sum += __shfl_xor(sum, m);
    const float mu = sum * (1.0f / 64.0f);
    const float dv = hv - mu;
    float vs = dv * dv;
    #pragma unroll
    for (int m = 32; m >= 1; m >>= 1) vs += __shfl_xor(vs, m);
    const float var = vs * (1.0f / 64.0f);

    out[(size_t)row * HID + o] = dv * rsqrtf(var + EPSF) * ln_g[o] + ln_b[o];
}

extern "C" void kernel_launch(void* const* d_in, const int* in_sizes, int n_in,
                              void* d_out, int out_size, void* d_ws, size_t ws_size,
                              hipStream_t stream) {
    const float* x     = (const float*)d_in[0];
    const float* amask = (const float*)d_in[1];
    const float* apk   = (const float*)d_in[2];
    const float* apv   = (const float*)d_in[3];
    const float* tk    = (const float*)d_in[4];
    const float* tv    = (const float*)d_in[5];
    const float* Wq    = (const float*)d_in[6];
    const float* bq    = (const float*)d_in[7];
    const float* Wk    = (const float*)d_in[8];
    const float* bk    = (const float*)d_in[9];
    const float* Wv    = (const float*)d_in[10];
    const float* bv    = (const float*)d_in[11];
    const float* Wd    = (const float*)d_in[12];
    const float* bd    = (const float*)d_in[13];
    const float* order_w = (const float*)d_in[14];
    const float* order_b = (const float*)d_in[15];
    const float* dist_w  = (const float*)d_in[16];
    const float* dist_b  = (const float*)d_in[17];
    const float* scalar  = (const float*)d_in[18];
    const float* ln_g    = (const float*)d_in[19];
    const float* ln_b    = (const float*)d_in[20];

    float* ws = (float*)d_ws;
    const size_t nrow = (size_t)B * N * HID;        // 819200
    const size_t nbh  = (size_t)B * NH * N;         // 6400
    float* qbuf   = ws;
    float* kpbuf  = qbuf  + nrow;
    float* vpbuf  = kpbuf + nrow;
    float* ctxtv  = vpbuf + nrow;
    float* ctxvp  = ctxtv + nrow;                   // nbh*D = 204800
    float* qob    = ctxvp + (size_t)nbh * D;
    float* kob    = qob + nbh;
    float* qdb    = kob + nbh;
    float* kdb    = qdb + nbh;
    float* Spre   = kdb + nbh;                      // nbh*N = 1.28M
    float* Pbuf   = Spre + (size_t)nbh * N;         // nbh*N = 1.28M

    k_proj<<<(B * N) / 4, 256, 0, stream>>>(x, apk, apv, Wq, bq, Wk, bk, Wv, bv,
                                            order_w, dist_w,
                                            qbuf, kpbuf, vpbuf, qob, kob, qdb, kdb);

    k_pre<<<B * NH * 8, 256, 0, stream>>>(qbuf, kpbuf, amask, qob, kob, qdb, kdb,
                                          order_b, dist_b, scalar, Spre);

    k_attn<<<B * NH * N, 64, 0, stream>>>(qbuf, tk, tv, Spre, Pbuf, ctxtv);

    k_pv<<<B * NH * 8, 256, 0, stream>>>(Pbuf, vpbuf, ctxvp);

    k_out<<<(B * N) / 4, 256, 0, stream>>>(ctxtv, ctxvp, x, Wd, bd, ln_g, ln_b,
                                           (float*)d_out);
}

// Round 7
// 146.535 us; speedup vs baseline: 1.0303x; 1.0303x over previous
//
#include <hip/hip_runtime.h>
#include <math.h>

#define B 16
#define N 200
#define HID 64
#define NH 2
#define D 32
#define EPSF 1e-12f

// 1/sqrt(32)
#define RSQRT_D 0.17677669529663687f

// ---------------- Kernel 1: projections + folded pos + order/dist scalars ----
__global__ __launch_bounds__(256) void k_proj(
    const float* __restrict__ x,
    const float* __restrict__ pk,
    const float* __restrict__ pv,
    const float* __restrict__ Wq, const float* __restrict__ bq,
    const float* __restrict__ Wk, const float* __restrict__ bk,
    const float* __restrict__ Wv, const float* __restrict__ bv,
    const float* __restrict__ order_w, const float* __restrict__ dist_w,
    float* __restrict__ q,
    float* __restrict__ kp,
    float* __restrict__ vp,
    float* __restrict__ qo, float* __restrict__ ko,
    float* __restrict__ qd, float* __restrict__ kd)
{
    __shared__ float sX[4][HID];
    const int tid = threadIdx.x;
    const int sub = tid >> 6;
    const int o   = tid & 63;
    const int row = blockIdx.x * 4 + sub;

    sX[sub][o] = x[row * HID + o];
    __syncthreads();

    float qv = bq[o], kv = bk[o], vv = bv[o];
    #pragma unroll 8
    for (int c = 0; c < HID; ++c) {
        const float xv = sX[sub][c];
        qv = fmaf(xv, Wq[o * HID + c], qv);
        kv = fmaf(xv, Wk[o * HID + c], kv);
        vv = fmaf(xv, Wv[o * HID + c], vv);
    }
    q [row * HID + o] = qv;
    kp[row * HID + o] = kv + pk[row * HID + o];
    vp[row * HID + o] = vv + pv[row * HID + o];

    const int d = o & 31;
    float qov = qv * order_w[d];
    float kov = kv * order_w[D + d];
    float qdv = qv * dist_w[d];
    float kdv = kv * dist_w[D + d];
    #pragma unroll
    for (int m = 16; m >= 1; m >>= 1) {
        qov += __shfl_xor(qov, m);
        kov += __shfl_xor(kov, m);
        qdv += __shfl_xor(qdv, m);
        kdv += __shfl_xor(kdv, m);
    }
    if (d == 0) {
        const int bb = row / N;
        const int ii = row - bb * N;
        const int h  = o >> 5;
        const int idx = (bb * NH + h) * N + ii;
        qo[idx] = qov;  ko[idx] = kov;
        qd[idx] = qdv;  kd[idx] = kdv;
    }
}

// ---------------- Kernel 2: S_pre[b,h,i,j] = (q.kp + order + dist)/sqrtD + mask
__global__ __launch_bounds__(256) void k_pre(
    const float* __restrict__ q, const float* __restrict__ kp,
    const float* __restrict__ amask,
    const float* __restrict__ qo, const float* __restrict__ ko,
    const float* __restrict__ qd, const float* __restrict__ kd,
    const float* __restrict__ order_b, const float* __restrict__ dist_b,
    const float* __restrict__ scalar,
    float* __restrict__ S_pre)        // [B*NH*N, N]
{
    __shared__ float sQ[25][33];
    __shared__ float sK[200][33];
    __shared__ float sGd[200];
    __shared__ float sQo[25], sQd[25];
    __shared__ float sKo[200], sKd[200];

    const int tid = threadIdx.x;
    const int bid = blockIdx.x;
    const int it  = bid & 7;          // i-tile
    const int bh  = bid >> 3;
    const int b   = bh >> 1;
    const int h   = bh & 1;
    const int i0  = it * 25;

    for (int e = tid; e < 200 * 32; e += 256) {
        const int j = e >> 5, d = e & 31;
        sK[j][d] = kp[((size_t)b * N + j) * HID + h * D + d];
    }
    for (int e = tid; e < 25 * 32; e += 256) {
        const int ii = e >> 5, d = e & 31;
        sQ[ii][d] = q[((size_t)b * N + i0 + ii) * HID + h * D + d];
    }
    for (int e = tid; e < 200; e += 256) {
        sGd[e] = logf((float)e + 1.0f);
        sKo[e] = ko[(size_t)bh * N + e];
        sKd[e] = kd[(size_t)bh * N + e];
    }
    if (tid < 25) {
        sQo[tid] = qo[(size_t)bh * N + i0 + tid];
        sQd[tid] = qd[(size_t)bh * N + i0 + tid];
    }
    const float ob = order_b[0];
    const float db = dist_b[0];
    const float sc = scalar[0];
    const float sc2h = 0.5f * sc * sc;
    __syncthreads();

    for (int e = tid; e < 25 * 200; e += 256) {
        const int ii = e / 200;
        const int jj = e - ii * 200;
        const int i  = i0 + ii;
        float dot = 0.0f;
        #pragma unroll
        for (int d = 0; d < 32; ++d)
            dot = fmaf(sQ[ii][d], sK[jj][d], dot);
        const float lo = sQo[ii] + sKo[jj] + ob;
        const float xs = (jj > i) ? -lo : lo;
        const float eo = -log1pf(expf(xs));
        const float pd = sQd[ii] + sKd[jj] + db;
        const int   ad = (jj > i) ? (jj - i) : (i - jj);
        const float dv = sGd[ad] - pd;
        const float ed = -sc2h * dv * dv;
        S_pre[((size_t)bh * N + i) * N + jj] =
            (dot + eo + ed) * RSQRT_D + amask[((size_t)b * N + i) * N + jj];
    }
}

// ---------------- Kernel 3: stream tk/tv (full rows); softmax; P; ctx_tv ----
// grid = B*N blocks, 64 threads = ONE WAVE per (b,i), BOTH heads.
// Lane = g*16 + c (g = row 0..3, c = float4 col 0..15 spanning the FULL 256B
// row). Every load instruction = 64 lanes x 16B = 1 KB contiguous, 100% line
// utilization. Loads issued in explicit 10-deep batches (MLP=10). Dot reduce
// via shfl within each c-octet (head = c>>3). Softmax: half-wave per head.
__global__ __launch_bounds__(64) void k_attn(
    const float* __restrict__ q,
    const float* __restrict__ tk,     // [B,N,N,HID]
    const float* __restrict__ tv,
    const float* __restrict__ S_pre,  // [B*NH*N, N]
    float* __restrict__ P,            // [B*NH*N, N]
    float* __restrict__ ctx_tv)       // [B*N, HID]
{
    __shared__ float S_dot[400];      // [head][200]
    __shared__ float SP[400];         // [head][200]

    const int lane = threadIdx.x;
    const int g    = lane >> 4;       // row in quad 0..3
    const int c    = lane & 15;       // float4 col 0..15 (head = c>>3)
    const int hd   = c >> 3;
    const int bi   = blockIdx.x;      // b*N + i
    const int b    = bi / N;
    const int i    = bi - b * N;

    // per-lane q fragment (covers both heads via c), pre-scaled
    float4 qf = ((const float4*)(q + (size_t)bi * HID))[c];
    qf.x *= RSQRT_D; qf.y *= RSQRT_D; qf.z *= RSQRT_D; qf.w *= RSQRT_D;

    const float4* tkR = (const float4*)(tk + (size_t)bi * N * HID);
    const float4* tvR = (const float4*)(tv + (size_t)bi * N * HID);

    // ---- phase B: 50 contiguous 1KB loads, batches of 10 ----
    #pragma unroll
    for (int bq = 0; bq < 5; ++bq) {
        float4 buf[10];
        #pragma unroll
        for (int u = 0; u < 10; ++u)
            buf[u] = tkR[(size_t)((bq * 10 + u) * 4 + g) * 16 + c];
        #pragma unroll
        for (int u = 0; u < 10; ++u) {
            const int j = (bq * 10 + u) * 4 + g;
            float part = qf.x * buf[u].x + qf.y * buf[u].y
                       + qf.z * buf[u].z + qf.w * buf[u].w;
            part += __shfl_xor(part, 1);
            part += __shfl_xor(part, 2);
            part += __shfl_xor(part, 4);   // octet-sum (per head)
            if ((c & 7) == 0) S_dot[hd * 200 + j] = part;
        }
    }
    asm volatile("s_waitcnt lgkmcnt(0)" ::: "memory");

    // ---- softmax: half-wave per head, 7 j's per lane ----
    {
        const int h2 = lane >> 5;         // this half-wave's head
        const int jl = lane & 31;
        const float* sprH = S_pre + ((size_t)(2 * b + h2) * N + i) * N;
        float sv[7];
        float mx = -INFINITY;
        #pragma unroll
        for (int r = 0; r < 7; ++r) {
            const int j = jl + 32 * r;
            sv[r] = (j < 200) ? (sprH[j] + S_dot[h2 * 200 + j]) : -INFINITY;
            mx = fmaxf(mx, sv[r]);
        }
        #pragma unroll
        for (int k = 16; k >= 1; k >>= 1) mx = fmaxf(mx, __shfl_xor(mx, k));
        float tt = 0.0f;
        #pragma unroll
        for (int r = 0; r < 7; ++r) {
            sv[r] = (jl + 32 * r < 200) ? expf(sv[r] - mx) : 0.0f;
            tt += sv[r];
        }
        #pragma unroll
        for (int k = 16; k >= 1; k >>= 1) tt += __shfl_xor(tt, k);
        const float rinv = 1.0f / tt;
        float* prowH = P + ((size_t)(2 * b + h2) * N + i) * N;
        #pragma unroll
        for (int r = 0; r < 7; ++r) {
            const int j = jl + 32 * r;
            const float pj = sv[r] * rinv;
            if (j < 200) { SP[h2 * 200 + j] = pj; prowH[j] = pj; }
        }
    }
    asm volatile("s_waitcnt lgkmcnt(0)" ::: "memory");

    // ---- phase C: ctx_tv = sum_j p_j * tv[i,j], batches of 10 ----
    float4 acc = make_float4(0.f, 0.f, 0.f, 0.f);
    #pragma unroll
    for (int bq = 0; bq < 5; ++bq) {
        float4 buf[10];
        #pragma unroll
        for (int u = 0; u < 10; ++u)
            buf[u] = tvR[(size_t)((bq * 10 + u) * 4 + g) * 16 + c];
        #pragma unroll
        for (int u = 0; u < 10; ++u) {
            const int j = (bq * 10 + u) * 4 + g;
            const float pj = SP[hd * 200 + j];
            acc.x = fmaf(pj, buf[u].x, acc.x);
            acc.y = fmaf(pj, buf[u].y, acc.y);
            acc.z = fmaf(pj, buf[u].z, acc.z);
            acc.w = fmaf(pj, buf[u].w, acc.w);
        }
    }
    // reduce across the 4 g-rows: xor 16, 32
    #pragma unroll
    for (int k = 16; k <= 32; k <<= 1) {
        acc.x += __shfl_xor(acc.x, k);
        acc.y += __shfl_xor(acc.y, k);
        acc.z += __shfl_xor(acc.z, k);
        acc.w += __shfl_xor(acc.w, k);
    }
    if (lane < 16)
        ((float4*)(ctx_tv + (size_t)bi * HID))[lane] = acc;
}

// ---------------- Kernel 4: ctx_vp[b,h,i,:] = sum_j P[b,h,i,j] * vp_h[b,j,:]
__global__ __launch_bounds__(256) void k_pv(
    const float* __restrict__ P, const float* __restrict__ vp,
    float* __restrict__ ctx_vp)       // [B*NH*N, D]
{
    __shared__ float sV[200][33];
    const int tid = threadIdx.x;
    const int bid = blockIdx.x;
    const int it  = bid & 7;
    const int bh  = bid >> 3;
    const int b   = bh >> 1;
    const int h   = bh & 1;
    const int i0  = it * 25;

    for (int e = tid; e < 200 * 32; e += 256) {
        const int j = e >> 5, d = e & 31;
        sV[j][d] = vp[((size_t)b * N + j) * HID + h * D + d];
    }
    __syncthreads();

    for (int e = tid; e < 25 * 32; e += 256) {
        const int ii = e >> 5, d = e & 31;
        const float* pr = P + ((size_t)bh * N + i0 + ii) * N;
        float acc = 0.0f;
        #pragma unroll 8
        for (int j = 0; j < 200; ++j)
            acc = fmaf(pr[j], sV[j][d], acc);
        ctx_vp[((size_t)bh * N + i0 + ii) * D + d] = acc;
    }
}

// ---------------- Kernel 5: combine + output proj + residual + LayerNorm ---
__global__ __launch_bounds__(256) void k_out(
    const float* __restrict__ ctx_tv, const float* __restrict__ ctx_vp,
    const float* __restrict__ x,
    const float* __restrict__ Wd, const float* __restrict__ bd,
    const float* __restrict__ ln_g, const float* __restrict__ ln_b,
    float* __restrict__ out)
{
    __shared__ float sC[4][HID];
    const int tid = threadIdx.x;
    const int sub = tid >> 6;
    const int o   = tid & 63;
    const int row = blockIdx.x * 4 + sub;
    const int b   = row / N;
    const int i   = row - b * N;
    const int h   = o >> 5;

    sC[sub][o] = ctx_tv[(size_t)row * HID + o]
               + ctx_vp[((size_t)(b * NH + h) * N + i) * D + (o & 31)];
    __syncthreads();

    float hv = bd[o] + x[(size_t)row * HID + o];
    #pragma unroll 8
    for (int c = 0; c < HID; ++c)
        hv = fmaf(sC[sub][c], Wd[o * HID + c], hv);

    float sum = hv;
    #pragma unroll
    for (int m = 32; m >= 1; m >>= 1) sum += __shfl_xor(sum, m);
    const float mu = sum * (1.0f / 64.0f);
    const float dv = hv - mu;
    float vs = dv * dv;
    #pragma unroll
    for (int m = 32; m >= 1; m >>= 1) vs += __shfl_xor(vs, m);
    const float var = vs * (1.0f / 64.0f);

    out[(size_t)row * HID + o] = dv * rsqrtf(var + EPSF) * ln_g[o] + ln_b[o];
}

extern "C" void kernel_launch(void* const* d_in, const int* in_sizes, int n_in,
                              void* d_out, int out_size, void* d_ws, size_t ws_size,
                              hipStream_t stream) {
    const float* x     = (const float*)d_in[0];
    const float* amask = (const float*)d_in[1];
    const float* apk   = (const float*)d_in[2];
    const float* apv   = (const float*)d_in[3];
    const float* tk    = (const float*)d_in[4];
    const float* tv    = (const float*)d_in[5];
    const float* Wq    = (const float*)d_in[6];
    const float* bq    = (const float*)d_in[7];
    const float* Wk    = (const float*)d_in[8];
    const float* bk    = (const float*)d_in[9];
    const float* Wv    = (const float*)d_in[10];
    const float* bv    = (const float*)d_in[11];
    const float* Wd    = (const float*)d_in[12];
    const float* bd    = (const float*)d_in[13];
    const float* order_w = (const float*)d_in[14];
    const float* order_b = (const float*)d_in[15];
    const float* dist_w  = (const float*)d_in[16];
    const float* dist_b  = (const float*)d_in[17];
    const float* scalar  = (const float*)d_in[18];
    const float* ln_g    = (const float*)d_in[19];
    const float* ln_b    = (const float*)d_in[20];

    float* ws = (float*)d_ws;
    const size_t nrow = (size_t)B * N * HID;        // 819200
    const size_t nbh  = (size_t)B * NH * N;         // 6400
    float* qbuf   = ws;
    float* kpbuf  = qbuf  + nrow;
    float* vpbuf  = kpbuf + nrow;
    float* ctxtv  = vpbuf + nrow;
    float* ctxvp  = ctxtv + nrow;                   // nbh*D = 204800
    float* qob    = ctxvp + (size_t)nbh * D;
    float* kob    = qob + nbh;
    float* qdb    = kob + nbh;
    float* kdb    = qdb + nbh;
    float* Spre   = kdb + nbh;                      // nbh*N = 1.28M
    float* Pbuf   = Spre + (size_t)nbh * N;         // nbh*N = 1.28M

    k_proj<<<(B * N) / 4, 256, 0, stream>>>(x, apk, apv, Wq, bq, Wk, bk, Wv, bv,
                                            order_w, dist_w,
                                            qbuf, kpbuf, vpbuf, qob, kob, qdb, kdb);

    k_pre<<<B * NH * 8, 256, 0, stream>>>(qbuf, kpbuf, amask, qob, kob, qdb, kdb,
                                          order_b, dist_b, scalar, Spre);

    k_attn<<<B * N, 64, 0, stream>>>(qbuf, tk, tv, Spre, Pbuf, ctxtv);

    k_pv<<<B * NH * 8, 256, 0, stream>>>(Pbuf, vpbuf, ctxvp);

    k_out<<<(B * N) / 4, 256, 0, stream>>>(ctxtv, ctxvp, x, Wd, bd, ln_g, ln_b,
                                           (float*)d_out);
}